// Round 2
// baseline (520.468 us; speedup 1.0000x reference)
//
#include <hip/hip_runtime.h>

#define NWIRES 14
#define DIM 16384            // 2^14 amplitudes
#define NLAYERS 3
#define NGATES (NLAYERS * NWIRES)   // 42
#define BLOCK 1024
#define PER_THREAD (DIM / BLOCK)          // 16 amplitudes/thread
#define PAIRS_PER_THREAD (DIM / 2 / BLOCK) // 8 butterfly pairs/thread/gate

// CNOTs are linear over GF(2) on index bits; we fold them into the gate
// pair-masks instead of moving data. For gate g:
//   m[g]  = XOR mask between butterfly partners (memory index space)
//   r[g]  = parity mask: logical-bit value at memory x = popc(x & r) & 1
//   h[g]  = pivot bit (highest set bit of m) used to enumerate pairs
//   zr[p] = final parity mask for logical bit position p (wire w = 13-p)
struct Masks {
    int m[NGATES];
    int r[NGATES];
    int h[NGATES];
    int zr[NWIRES];
};

__global__ __launch_bounds__(BLOCK) void qsim_kernel(
    const float* __restrict__ g_sr, const float* __restrict__ g_si,
    const float* __restrict__ g_params, const float* __restrict__ g_hw,
    const float* __restrict__ g_hb, float* __restrict__ g_out, Masks mk)
{
    extern __shared__ float smem[];
    float* sr = smem;        // DIM floats
    float* si = smem + DIM;  // DIM floats
    __shared__ float gm[NGATES * 8];   // per gate: u00r,u00i,u01r,u01i,u10r,u10i,u11r,u11i
    __shared__ float red[BLOCK / 64];

    const int tid = threadIdx.x;
    const int b = blockIdx.x;

    // ---- load state into LDS (coalesced) ----
    const float* __restrict__ srcr = g_sr + (size_t)b * DIM;
    const float* __restrict__ srci = g_si + (size_t)b * DIM;
    #pragma unroll
    for (int it = 0; it < PER_THREAD; ++it) {
        int x = tid + it * BLOCK;
        sr[x] = srcr[x];
        si[x] = srci[x];
    }

    // ---- build gate matrices U = RZ(z) @ RY(y) @ RX(x), one gate per thread ----
    if (tid < NGATES) {
        float tx = g_params[tid * 3 + 0];
        float ty = g_params[tid * 3 + 1];
        float tz = g_params[tid * 3 + 2];
        float cx = cosf(0.5f * tx), sx = sinf(0.5f * tx);
        float cy = cosf(0.5f * ty), sy = sinf(0.5f * ty);
        float cz = cosf(0.5f * tz), sz = sinf(0.5f * tz);
        // A = RY@RX:
        // a00 = cy*cx + i*sy*sx        a01 = -sy*cx - i*cy*sx
        // a10 = sy*cx - i*cy*sx        a11 = cy*cx - i*sy*sx
        float a00r = cy * cx,  a00i = sy * sx;
        float a01r = -sy * cx, a01i = -cy * sx;
        float a10r = sy * cx,  a10i = -cy * sx;
        float a11r = cy * cx,  a11i = -sy * sx;
        // row0 *= e^{-iz/2} = (cz - i sz);  row1 *= e^{+iz/2} = (cz + i sz)
        gm[tid * 8 + 0] = cz * a00r + sz * a00i;
        gm[tid * 8 + 1] = cz * a00i - sz * a00r;
        gm[tid * 8 + 2] = cz * a01r + sz * a01i;
        gm[tid * 8 + 3] = cz * a01i - sz * a01r;
        gm[tid * 8 + 4] = cz * a10r - sz * a10i;
        gm[tid * 8 + 5] = cz * a10i + sz * a10r;
        gm[tid * 8 + 6] = cz * a11r - sz * a11i;
        gm[tid * 8 + 7] = cz * a11i + sz * a11r;
    }
    __syncthreads();

    // ---- 42 butterfly passes (CNOTs folded into masks) ----
    for (int g = 0; g < NGATES; ++g) {
        const float u00r = gm[g * 8 + 0], u00i = gm[g * 8 + 1];
        const float u01r = gm[g * 8 + 2], u01i = gm[g * 8 + 3];
        const float u10r = gm[g * 8 + 4], u10i = gm[g * 8 + 5];
        const float u11r = gm[g * 8 + 6], u11i = gm[g * 8 + 7];
        const int m = mk.m[g];
        const int r = mk.r[g];
        const int h = mk.h[g];
        const int lowmask = (1 << h) - 1;

        #pragma unroll
        for (int it = 0; it < PAIRS_PER_THREAD; ++it) {
            int j = tid + it * BLOCK;                       // pair id in [0, 8192)
            int x0 = ((j >> h) << (h + 1)) | (j & lowmask); // pivot bit = 0
            int x1 = x0 ^ m;                                // pivot bit = 1
            int par = __popc(x0 & r) & 1;                   // logical bit value at x0

            float b0r = sr[x0], b0i = si[x0];
            float b1r = sr[x1], b1i = si[x1];
            // a0 = amplitude with logical bit 0, a1 with logical bit 1
            float a0r = par ? b1r : b0r, a0i = par ? b1i : b0i;
            float a1r = par ? b0r : b1r, a1i = par ? b0i : b1i;

            float n0r = u00r * a0r - u00i * a0i + u01r * a1r - u01i * a1i;
            float n0i = u00r * a0i + u00i * a0r + u01r * a1i + u01i * a1r;
            float n1r = u10r * a0r - u10i * a0i + u11r * a1r - u11i * a1i;
            float n1i = u10r * a0i + u10i * a0r + u11r * a1i + u11i * a1r;

            sr[x0] = par ? n1r : n0r;  si[x0] = par ? n1i : n0i;
            sr[x1] = par ? n0r : n1r;  si[x1] = par ? n0i : n1i;
        }
        __syncthreads();
    }

    // ---- epilogue: out[b] = sum_x |psi[x]|^2 * c(x) + bias,
    //      c(x) = sum_w hw[w] * (1 - 2*parity(x & zr[13-w])) ----
    float hw[NWIRES];
    #pragma unroll
    for (int w = 0; w < NWIRES; ++w) hw[w] = g_hw[w];

    float acc = 0.0f;
    #pragma unroll
    for (int it = 0; it < PER_THREAD; ++it) {
        int x = tid + it * BLOCK;
        float pr = sr[x] * sr[x] + si[x] * si[x];
        float c = 0.0f;
        #pragma unroll
        for (int p = 0; p < NWIRES; ++p) {
            float hv = hw[13 - p];
            int par = __popc(x & mk.zr[p]) & 1;
            c += par ? -hv : hv;
        }
        acc += pr * c;
    }
    // wave (64-lane) reduction, then cross-wave via LDS
    #pragma unroll
    for (int off = 32; off > 0; off >>= 1) acc += __shfl_down(acc, off);
    int lane = tid & 63, wid = tid >> 6;
    if (lane == 0) red[wid] = acc;
    __syncthreads();
    if (tid == 0) {
        float s = 0.0f;
        #pragma unroll
        for (int k = 0; k < BLOCK / 64; ++k) s += red[k];
        g_out[b] = s + g_hb[0];
    }
}

static void compute_masks(Masks& mk) {
    int R[NWIRES], C[NWIRES];
    for (int p = 0; p < NWIRES; ++p) { R[p] = 1 << p; C[p] = 1 << p; }
    int g = 0;
    for (int l = 0; l < NLAYERS; ++l) {
        for (int w = 0; w < NWIRES; ++w) {
            int p = 13 - w;  // wire w lives at bit position 13-w (wire 0 = MSB)
            mk.m[g] = C[p];
            mk.r[g] = R[p];
            mk.h[g] = 31 - __builtin_clz((unsigned)C[p]);
            ++g;
        }
        // CNOT chain: (w, w+1) for w=0..12, then (13, 0). Update f <- sigma o f:
        //   rows:    R[pt] ^= R[pc];    cols of f^{-1}: C[pc] ^= C[pt]
        for (int w = 0; w < NWIRES; ++w) {
            int c = w, t = (w + 1) % NWIRES;
            int pc = 13 - c, pt = 13 - t;
            R[pt] ^= R[pc];
            C[pc] ^= C[pt];
        }
    }
    for (int p = 0; p < NWIRES; ++p) mk.zr[p] = R[p];
}

extern "C" void kernel_launch(void* const* d_in, const int* in_sizes, int n_in,
                              void* d_out, int out_size, void* d_ws, size_t ws_size,
                              hipStream_t stream) {
    const float* sr = (const float*)d_in[0];
    const float* si = (const float*)d_in[1];
    const float* vp = (const float*)d_in[2];
    const float* hw = (const float*)d_in[3];
    const float* hb = (const float*)d_in[4];
    float* out = (float*)d_out;

    Masks mk;
    compute_masks(mk);

    dim3 grid(out_size);   // 1024 batch elements, one block each
    dim3 block(BLOCK);
    size_t shmem = (size_t)2 * DIM * sizeof(float);  // 128 KiB dynamic LDS
    qsim_kernel<<<grid, block, shmem, stream>>>(sr, si, vp, hw, hb, out, mk);
}

// Round 3
// 461.315 us; speedup vs baseline: 1.1282x; 1.1282x over previous
//
#include <hip/hip_runtime.h>

#define NW 14
#define NL 3
#define NGAT 42            // 3 layers x 14 rotation gates
#define DIM 16384          // 2^14 amplitudes
#define BLOCK 1024
#define NBATCH 12          // 3 layers x batches of (4,4,4,2) gates

// ---------------------------------------------------------------------------
// Compile-time circuit plan. CNOTs are linear over GF(2) on index bits; we
// track L (memory->logical map): R[p] = row p of L (parity mask giving logical
// bit p's value), C[p] = column p of L^{-1} (XOR mask pairing the butterfly for
// logical bit p). All of this is input-independent -> constexpr.
//
// Register blocking: each thread owns a coset of V = span(batch's 4 gate
// masks); element e of its 16 registers sits at memory index
//   x_e = rep ^ combo[e],  combo[e] = XOR of basis vectors selected by bits(e)
// Gate j pairs register slots e <-> e^(1<<j)  (static indices!).
// rep = deposit(tid) into the 10 non-pivot bit positions of V's echelon form.
// LDS layout is float2-interleaved and XOR-swizzled: slot = sigma(x),
//   sigma(x) = x ^ (x>>5) ^ (x>>10)   (invertible, banks spread for any batch)
// ---------------------------------------------------------------------------

constexpr unsigned sigma(unsigned x) { return (x ^ (x >> 5) ^ (x >> 10)) & (DIM - 1); }

constexpr int parity14(int v) { int p = 0; for (int i = 0; i < NW; ++i) p ^= (v >> i) & 1; return p; }
constexpr int hibit(int v) { int h = -1; for (int i = 0; i < NW; ++i) if ((v >> i) & 1) h = i; return h; }

struct Gate {
    int gidx;        // index into gm LDS array (l*14 + w)
    unsigned pm;     // bit e: parity(combo[e] & r)  -> which coeff set slot e uses
    unsigned tpar;   // tid-bit mask: prep = popc(tid & tpar) & 1  (= parity(rep & r))
};
struct Batch {
    int ngates;
    Gate g[4];
    unsigned scomboB[16];  // sigma(combo[e]) * 8   (LDS byte offsets)
    unsigned srepcB[10];   // sigma(1<<nppos[k]) * 8 (per-tid-bit deposit constants)
};
struct Plan {
    Batch b[NBATCH];
    unsigned ztid[NW];  // tid parity mask for wire w's final Z sign (last batch coset)
    unsigned zpm[NW];   // bit e: parity(combo_last[e] & zr_w)
};

constexpr Plan make_plan() {
    Plan P{};
    int R[NW] = {}, C[NW] = {};
    for (int p = 0; p < NW; ++p) { R[p] = 1 << p; C[p] = 1 << p; }
    int bi = 0;
    int lastNpp[10] = {}; int lastCombo[16] = {};
    for (int l = 0; l < NL; ++l) {
        const int sizes[4] = {4, 4, 4, 2};
        int w0 = 0;
        for (int s = 0; s < 4; ++s) {
            Batch& B = P.b[bi];
            int ng = sizes[s];
            B.ngates = ng;
            int basis[4] = {}, rr[4] = {};
            for (int j = 0; j < ng; ++j) {
                int w = w0 + j, p = 13 - w;
                basis[j] = C[p];
                rr[j] = R[p];
                B.g[j].gidx = l * NW + w;
            }
            // echelon of gate masks (they are linearly independent within a layer)
            int ech[4] = {}; int ne = 0;
            for (int j = 0; j < ng; ++j) {
                int v = basis[j];
                bool ch = true;
                while (ch) { ch = false;
                    for (int k = 0; k < ne; ++k)
                        if (v && ((v >> hibit(ech[k])) & 1)) { v ^= ech[k]; ch = true; }
                }
                ech[ne++] = v;
            }
            // pad basis to 4 with independent unit vectors (inert register bits)
            int nb = ng;
            for (int bit = 0; bit < NW && nb < 4; ++bit) {
                int v = 1 << bit;
                bool ch = true;
                while (ch) { ch = false;
                    for (int k = 0; k < ne; ++k)
                        if (v && ((v >> hibit(ech[k])) & 1)) { v ^= ech[k]; ch = true; }
                }
                if (v) { basis[nb++] = 1 << bit; ech[ne++] = v; }
            }
            // pivots & non-pivot deposit positions
            int piv[4] = {};
            for (int k = 0; k < 4; ++k) piv[k] = hibit(ech[k]);
            for (int a = 0; a < 4; ++a)
                for (int b2 = a + 1; b2 < 4; ++b2)
                    if (piv[b2] < piv[a]) { int t = piv[a]; piv[a] = piv[b2]; piv[b2] = t; }
            int npp[10] = {}; int nn = 0;
            for (int bit = 0; bit < NW; ++bit) {
                bool isp = false;
                for (int k = 0; k < 4; ++k) if (piv[k] == bit) isp = true;
                if (!isp) npp[nn++] = bit;
            }
            // coset offsets
            int combo[16] = {};
            for (int e = 0; e < 16; ++e) {
                int v = 0;
                for (int j = 0; j < 4; ++j) if ((e >> j) & 1) v ^= basis[j];
                combo[e] = v;
                B.scomboB[e] = sigma((unsigned)v) * 8u;
            }
            for (int k = 0; k < 10; ++k) B.srepcB[k] = sigma(1u << npp[k]) * 8u;
            // per-gate parity metadata
            for (int j = 0; j < ng; ++j) {
                unsigned pm = 0, tp = 0;
                for (int e = 0; e < 16; ++e) pm |= (unsigned)parity14(combo[e] & rr[j]) << e;
                for (int k = 0; k < 10; ++k) tp |= (unsigned)((rr[j] >> npp[k]) & 1) << k;
                B.g[j].pm = pm; B.g[j].tpar = tp;
            }
            if (bi == NBATCH - 1) {
                for (int k = 0; k < 10; ++k) lastNpp[k] = npp[k];
                for (int e = 0; e < 16; ++e) lastCombo[e] = combo[e];
            }
            w0 += ng;
            ++bi;
        }
        // CNOT chain (w,w+1) w=0..12 then (13,0): L <- sigma o L
        for (int w = 0; w < NW; ++w) {
            int c = w, t = (w + 1) % NW;
            int pc = 13 - c, pt = 13 - t;
            R[pt] ^= R[pc];
            C[pc] ^= C[pt];
        }
    }
    for (int w = 0; w < NW; ++w) {
        int zrw = R[13 - w];
        unsigned tz = 0, zp = 0;
        for (int k = 0; k < 10; ++k) tz |= (unsigned)((zrw >> lastNpp[k]) & 1) << k;
        for (int e = 0; e < 16; ++e) zp |= (unsigned)parity14(lastCombo[e] & zrw) << e;
        P.ztid[w] = tz; P.zpm[w] = zp;
    }
    return P;
}

constexpr Plan PLAN = make_plan();

__device__ __forceinline__ unsigned sigma_rt(unsigned x) { return x ^ (x >> 5) ^ (x >> 10); }

// Apply gate J of batch BI to the 16 register amplitudes. All parity-driven
// coefficient choices are compile-time; inner math is pure FMA.
template <int BI, int J>
__device__ __forceinline__ void apply_gates(float2 (&amp)[16], const float* gm, unsigned tid) {
    if constexpr (J < PLAN.b[BI].ngates) {
        constexpr Gate G = PLAN.b[BI].g[J];
        const float4 u0 = *(const float4*)&gm[G.gidx * 8];      // u00r,u00i,u01r,u01i
        const float4 u1 = *(const float4*)&gm[G.gidx * 8 + 4];  // u10r,u10i,u11r,u11i
        const bool p = (__popc(tid & G.tpar) & 1) != 0;
        // coeff set 0: for elements with pm-bit 0 (logical bit = prep)
        const float c0dr = p ? u1.z : u0.x, c0di = p ? u1.w : u0.y;
        const float c0or = p ? u1.x : u0.z, c0oi = p ? u1.y : u0.w;
        // coeff set 1: for elements with pm-bit 1 (logical bit = 1-prep)
        const float c1dr = p ? u0.x : u1.z, c1di = p ? u0.y : u1.w;
        const float c1or = p ? u0.z : u1.x, c1oi = p ? u0.w : u1.y;
        #pragma unroll
        for (int e = 0; e < 16; ++e) {
            if ((e >> J) & 1) continue;
            const int f = e | (1 << J);
            const float2 ae = amp[e], af = amp[f];
            float edr, edi, eor, eoi, fdr, fdi, fror, froi;
            if ((G.pm >> e) & 1) {
                edr = c1dr; edi = c1di; eor = c1or; eoi = c1oi;
                fdr = c0dr; fdi = c0di; fror = c0or; froi = c0oi;
            } else {
                edr = c0dr; edi = c0di; eor = c0or; eoi = c0oi;
                fdr = c1dr; fdi = c1di; fror = c1or; froi = c1oi;
            }
            amp[e].x = edr * ae.x - edi * ae.y + eor * af.x - eoi * af.y;
            amp[e].y = edr * ae.y + edi * ae.x + eor * af.y + eoi * af.x;
            amp[f].x = fdr * af.x - fdi * af.y + fror * ae.x - froi * ae.y;
            amp[f].y = fdr * af.y + fdi * af.x + fror * ae.y + froi * ae.x;
        }
        apply_gates<BI, J + 1>(amp, gm, tid);
    }
}

template <int BI>
__device__ __forceinline__ void run_batches(char* lds, const float* gm, unsigned tid,
                                            const float* g_hw, float& acc) {
    if constexpr (BI < NBATCH) {
        constexpr Batch B = PLAN.b[BI];
        __syncthreads();   // previous writes (or initial load) visible
        unsigned srep = 0;
        #pragma unroll
        for (int k = 0; k < 10; ++k)
            srep ^= (unsigned)(-(int)((tid >> k) & 1u)) & B.srepcB[k];
        unsigned adr[16];
        #pragma unroll
        for (int e = 0; e < 16; ++e) adr[e] = srep ^ B.scomboB[e];
        float2 amp[16];
        #pragma unroll
        for (int e = 0; e < 16; ++e) amp[e] = *(const float2*)(lds + adr[e]);
        apply_gates<BI, 0>(amp, gm, tid);
        if constexpr (BI == NBATCH - 1) {
            // epilogue straight from registers: acc += |psi|^2 * c(x_e)
            float s[NW];
            #pragma unroll
            for (int w = 0; w < NW; ++w) {
                const bool pz = (__popc(tid & PLAN.ztid[w]) & 1) != 0;
                const float hv = g_hw[w];
                s[w] = pz ? -hv : hv;
            }
            #pragma unroll
            for (int e = 0; e < 16; ++e) {
                const float pr = amp[e].x * amp[e].x + amp[e].y * amp[e].y;
                float c = 0.f;
                #pragma unroll
                for (int w = 0; w < NW; ++w)
                    c += ((PLAN.zpm[w] >> e) & 1) ? -s[w] : s[w];
                acc += pr * c;
            }
        } else {
            #pragma unroll
            for (int e = 0; e < 16; ++e) *(float2*)(lds + adr[e]) = amp[e];
            run_batches<BI + 1>(lds, gm, tid, g_hw, acc);
        }
    }
}

__global__ __launch_bounds__(BLOCK) void qsim_kernel(
    const float* __restrict__ g_sr, const float* __restrict__ g_si,
    const float* __restrict__ g_params, const float* __restrict__ g_hw,
    const float* __restrict__ g_hb, float* __restrict__ g_out)
{
    extern __shared__ char lds[];                  // DIM * 8 B: float2-interleaved, sigma-swizzled
    __shared__ __align__(16) float gm[NGAT * 8];   // per gate: u00,u01,u10,u11 (complex)
    __shared__ float red[BLOCK / 64];

    const unsigned tid = threadIdx.x;
    const int b = blockIdx.x;
    const float* __restrict__ srcr = g_sr + (size_t)b * DIM;
    const float* __restrict__ srci = g_si + (size_t)b * DIM;

    // ---- gate matrices U = RZ @ RY @ RX, one gate per thread ----
    if (tid < NGAT) {
        const float tx = g_params[tid * 3 + 0];
        const float ty = g_params[tid * 3 + 1];
        const float tz = g_params[tid * 3 + 2];
        const float cx = cosf(0.5f * tx), sx = sinf(0.5f * tx);
        const float cy = cosf(0.5f * ty), sy = sinf(0.5f * ty);
        const float cz = cosf(0.5f * tz), sz = sinf(0.5f * tz);
        const float a00r = cy * cx,  a00i = sy * sx;
        const float a01r = -sy * cx, a01i = -cy * sx;
        const float a10r = sy * cx,  a10i = -cy * sx;
        const float a11r = cy * cx,  a11i = -sy * sx;
        gm[tid * 8 + 0] = cz * a00r + sz * a00i;
        gm[tid * 8 + 1] = cz * a00i - sz * a00r;
        gm[tid * 8 + 2] = cz * a01r + sz * a01i;
        gm[tid * 8 + 3] = cz * a01i - sz * a01r;
        gm[tid * 8 + 4] = cz * a10r - sz * a10i;
        gm[tid * 8 + 5] = cz * a10i + sz * a10r;
        gm[tid * 8 + 6] = cz * a11r - sz * a11i;
        gm[tid * 8 + 7] = cz * a11i + sz * a11r;
    }

    // ---- load state: coalesced float4 global reads -> interleaved swizzled LDS ----
    #pragma unroll
    for (int it = 0; it < 4; ++it) {
        const int x = (int)tid * 4 + it * 4096;
        const float4 re = *(const float4*)(srcr + x);
        const float4 im = *(const float4*)(srci + x);
        ((float2*)lds)[sigma_rt(x + 0)] = make_float2(re.x, im.x);
        ((float2*)lds)[sigma_rt(x + 1)] = make_float2(re.y, im.y);
        ((float2*)lds)[sigma_rt(x + 2)] = make_float2(re.z, im.z);
        ((float2*)lds)[sigma_rt(x + 3)] = make_float2(re.w, im.w);
    }

    float acc = 0.0f;
    run_batches<0>(lds, gm, tid, g_hw, acc);

    // ---- reduce: wave shuffle then cross-wave via LDS ----
    #pragma unroll
    for (int off = 32; off > 0; off >>= 1) acc += __shfl_down(acc, off);
    const int lane = tid & 63, wid = tid >> 6;
    if (lane == 0) red[wid] = acc;
    __syncthreads();
    if (tid == 0) {
        float s = 0.0f;
        #pragma unroll
        for (int k = 0; k < BLOCK / 64; ++k) s += red[k];
        g_out[b] = s + g_hb[0];
    }
}

extern "C" void kernel_launch(void* const* d_in, const int* in_sizes, int n_in,
                              void* d_out, int out_size, void* d_ws, size_t ws_size,
                              hipStream_t stream) {
    const float* sr = (const float*)d_in[0];
    const float* si = (const float*)d_in[1];
    const float* vp = (const float*)d_in[2];
    const float* hw = (const float*)d_in[3];
    const float* hb = (const float*)d_in[4];
    float* out = (float*)d_out;

    dim3 grid(out_size);          // 1024 batch elements, one block each
    dim3 block(BLOCK);
    size_t shmem = (size_t)DIM * sizeof(float2);  // 128 KiB dynamic LDS
    qsim_kernel<<<grid, block, shmem, stream>>>(sr, si, vp, hw, hb, out);
}